// Round 10
// baseline (630.629 us; speedup 1.0000x reference)
//
#include <hip/hip_runtime.h>
#include <stdint.h>

// TripletRankingLoss, bit-exact JAX threefry (partitionable) replication.
// R10: single fused dispatch. R9 showed ~10us per dispatch gap (4 dispatches,
// ~50us non-rows time). Here: blocks 0-7 hist -> block 8 scan -> blocks 0-7
// scatter -> all 2048 blocks rows, synced by MAGIC-flag spins in d_ws
// (poison 0xAA != MAGIC). Deadlock-free: __launch_bounds__(256,8) => VGPR<=64
// => all 2048 blocks co-resident (LDS 4.2KB). rows logic identical to R8/R9;
// unroll-8 BANNED (poisoned R5-R7). ws watermark 57.1KB (= R9 proven).

#define B 8192
#define K 1024
#define HB 8
#define MAGIC1 0x13579BDFu   // hist-done flag value
#define MAGIC2 0x2468ACE0u   // scan-done flag value

struct TFOut { uint32_t a, b; };

__host__ __device__ constexpr uint32_t rotl32(uint32_t x, int r) {
    return (x << r) | (x >> (32 - r));
}

// Full Threefry-2x32 (20 rounds), exactly as jax/_src/prng.py — compile-time
// only, to derive the split keys.
__host__ __device__ constexpr TFOut threefry_full(uint32_t k0, uint32_t k1,
                                                  uint32_t x0, uint32_t x1) {
    const uint32_t ks2 = k0 ^ k1 ^ 0x1BD11BDAu;
    x0 += k0; x1 += k1;
    x0 += x1; x1 = rotl32(x1,13); x1 ^= x0;
    x0 += x1; x1 = rotl32(x1,15); x1 ^= x0;
    x0 += x1; x1 = rotl32(x1,26); x1 ^= x0;
    x0 += x1; x1 = rotl32(x1,6);  x1 ^= x0;
    x0 += k1; x1 += ks2 + 1u;
    x0 += x1; x1 = rotl32(x1,17); x1 ^= x0;
    x0 += x1; x1 = rotl32(x1,29); x1 ^= x0;
    x0 += x1; x1 = rotl32(x1,16); x1 ^= x0;
    x0 += x1; x1 = rotl32(x1,24); x1 ^= x0;
    x0 += ks2; x1 += k0 + 2u;
    x0 += x1; x1 = rotl32(x1,13); x1 ^= x0;
    x0 += x1; x1 = rotl32(x1,15); x1 ^= x0;
    x0 += x1; x1 = rotl32(x1,26); x1 ^= x0;
    x0 += x1; x1 = rotl32(x1,6);  x1 ^= x0;
    x0 += k0; x1 += k1 + 3u;
    x0 += x1; x1 = rotl32(x1,17); x1 ^= x0;
    x0 += x1; x1 = rotl32(x1,29); x1 ^= x0;
    x0 += x1; x1 = rotl32(x1,16); x1 ^= x0;
    x0 += x1; x1 = rotl32(x1,24); x1 ^= x0;
    x0 += k1; x1 += ks2 + 4u;
    x0 += x1; x1 = rotl32(x1,13); x1 ^= x0;
    x0 += x1; x1 = rotl32(x1,15); x1 ^= x0;
    x0 += x1; x1 = rotl32(x1,26); x1 ^= x0;
    x0 += x1; x1 = rotl32(x1,6);  x1 ^= x0;
    x0 += ks2; x1 += k0 + 5u;
    return TFOut{x0, x1};
}

// jax.random.key(42) -> (0,42); partitionable split: kp=block(0,0), kn=block(0,1).
constexpr TFOut KP = threefry_full(0u, 42u, 0u, 0u);
constexpr TFOut KN = threefry_full(0u, 42u, 0u, 1u);

// Device-fast threefry: x0=0 implicit, keys compile-time, caller passes
// x1 pre-keyed (= f + K1). alignbit guarantees 1-inst rotates.
template<uint32_t TK0, uint32_t TK1>
__device__ __forceinline__ uint32_t tf_bits(uint32_t x1) {
    constexpr uint32_t KS2 = TK0 ^ TK1 ^ 0x1BD11BDAu;
    uint32_t x0 = TK0;
#define RND(r) x0 += x1; x1 = __builtin_amdgcn_alignbit(x1, x1, 32 - (r)); x1 ^= x0;
    RND(13) RND(15) RND(26) RND(6)
    x0 += TK1; x1 += KS2 + 1u;
    RND(17) RND(29) RND(16) RND(24)
    x0 += KS2; x1 += TK0 + 2u;
    RND(13) RND(15) RND(26) RND(6)
    x0 += TK0; x1 += TK1 + 3u;
    RND(17) RND(29) RND(16) RND(24)
    x0 += TK1; x1 += KS2 + 4u;
    RND(13) RND(15) RND(26) RND(6)
    x0 += KS2; x1 += TK0 + 5u;
#undef RND
    return x0 ^ x1;
}

__device__ __forceinline__ void mrg(uint32_t& H, uint32_t& J, uint32_t h2, uint32_t j2) {
    if (h2 > H || (h2 == H && j2 < J)) { H = h2; J = j2; }  // j tie: smaller wins
}

// Unchecked-zone scan: unroll-4, preload next group (over-read <= entry
// end+255, covered by the slack region after sorted_idx).
template<uint32_t TK0, uint32_t TK1>
__device__ __forceinline__ void scan_main(const uint16_t* __restrict__ idx,
                                          int beg, int end, int lane,
                                          uint32_t kb, uint32_t& H, uint32_t& J)
{
    uint32_t h0 = 0, h1 = 0, h2 = 0, h3 = 0;
    uint32_t j0 = 0xFFFFFFFFu, j1 = 0xFFFFFFFFu, j2 = 0xFFFFFFFFu, j3 = 0xFFFFFFFFu;
    int s = beg;
    uint32_t a = 0, b = 0, c = 0, d = 0;
    if (s + 256 <= end) {
        a = idx[s + lane];       b = idx[s + lane + 64];
        c = idx[s + lane + 128]; d = idx[s + lane + 192];
    }
    while (s + 256 <= end) {
        const int sn = s + 256;
        const uint32_t na = idx[sn + lane];        // in flight across the 4 hashes
        const uint32_t nb = idx[sn + lane + 64];
        const uint32_t nc = idx[sn + lane + 128];
        const uint32_t nd = idx[sn + lane + 192];
        const uint32_t ha = tf_bits<TK0, TK1>(a + kb) >> 9;
        const uint32_t hb = tf_bits<TK0, TK1>(b + kb) >> 9;
        const uint32_t hc = tf_bits<TK0, TK1>(c + kb) >> 9;
        const uint32_t hd = tf_bits<TK0, TK1>(d + kb) >> 9;
        if (ha > h0) { h0 = ha; j0 = a; }
        if (hb > h1) { h1 = hb; j1 = b; }
        if (hc > h2) { h2 = hc; j2 = c; }
        if (hd > h3) { h3 = hd; j3 = d; }
        a = na; b = nb; c = nc; d = nd;
        s = sn;
    }
    for (int t = s + lane; t < end; t += 64) {
        const uint32_t j = idx[t];
        const uint32_t hh = tf_bits<TK0, TK1>(j + kb) >> 9;
        if (hh > h0) { h0 = hh; j0 = j; }
    }
    mrg(h0, j0, h1, j1); mrg(h2, j2, h3, j3); mrg(h0, j0, h2, j2);
    mrg(H, J, h0, j0);
}

// Boundary zone (~16 elems/row): exact fp32 predicate per element.
template<uint32_t TK0, uint32_t TK1, bool NEG>
__device__ __forceinline__ void scan_bnd(const float* __restrict__ st,
                                         const uint16_t* __restrict__ idx,
                                         int beg, int end, int lane, float ti,
                                         uint32_t kb, uint32_t& H, uint32_t& J,
                                         bool& found)
{
    for (int t = beg + lane; t < end; t += 64) {
        const float tj = st[t];
        const uint32_t j = idx[t];
        const uint32_t hh = tf_bits<TK0, TK1>(j + kb) >> 9;
        const float dd = ti - tj;
        const bool ok = NEG ? (dd > 0.1f) : (dd < -0.1f);
        if (ok) {
            found = true;
            if (hh > H || (hh == H && j < J)) { H = hh; J = j; }
        }
    }
}

__device__ __forceinline__ int bin_of(float v) {
    int b = (int)(v * (float)K);
    return b < 0 ? 0 : (b > K - 1 ? K - 1 : b);
}

__device__ __forceinline__ void spin_eq(unsigned int* p, unsigned int v) {
    while (__hip_atomic_load(p, __ATOMIC_ACQUIRE, __HIP_MEMORY_SCOPE_AGENT) != v)
        __builtin_amdgcn_s_sleep(2);
}

// ---------------- Single fused kernel ----------------------------------------
// __launch_bounds__(256, 8): 8 waves/EU => VGPR<=64 => 8 blocks/CU => all 2048
// blocks co-resident => every spin's producer is resident (deadlock-free).
__global__ __launch_bounds__(256, 8) void fused_kernel(
    const float* __restrict__ preds, const float* __restrict__ targets,
    float* __restrict__ sorted_t, uint16_t* __restrict__ sorted_idx,
    uint16_t* __restrict__ blockHist, int* __restrict__ bin_start,
    int* __restrict__ cursor, unsigned int* __restrict__ hist_flags,
    unsigned int* __restrict__ scan_flag, unsigned int* __restrict__ scat_cnt,
    float* __restrict__ loss_sum, float* __restrict__ valid_sum,
    unsigned int* __restrict__ done, float* __restrict__ out)
{
    __shared__ int hsh[K];        // sort histogram (blocks 0..7 only)
    __shared__ int wsum[4];
    __shared__ float sl[4], sv[4];
    const int tid = threadIdx.x;
    const int bid = blockIdx.x;

    // ================= sort prologue (blocks 0..8) =================
    if (bid < HB) {
        // --- histogram of own 1024-elem chunk into private u16 slab ---
        for (int i = tid; i < K; i += 256) hsh[i] = 0;
        __syncthreads();
        const int cbase = bid * (B / HB);
        for (int i = 0; i < (B / HB) / 256; ++i)
            atomicAdd(&hsh[bin_of(targets[cbase + tid + i * 256])], 1);
        __syncthreads();
        for (int i = tid; i < K; i += 256)            // slab fully overwritten
            blockHist[bid * K + i] = (uint16_t)hsh[i];
        __threadfence();
        __syncthreads();
        if (tid == 0)
            __hip_atomic_store(&hist_flags[bid], MAGIC1, __ATOMIC_RELEASE,
                               __HIP_MEMORY_SCOPE_AGENT);
        // --- wait for scan, then scatter own chunk ---
        if (tid == 0) spin_eq(scan_flag, MAGIC2);
        __syncthreads();
        __threadfence();
        for (int i = 0; i < (B / HB) / 256; ++i) {
            const int e = cbase + tid + i * 256;
            const float v = targets[e];
            const int p = atomicAdd(&cursor[bin_of(v)], 1);
            sorted_t[p]   = v;
            sorted_idx[p] = (uint16_t)e;
        }
        __threadfence();
        __syncthreads();
        if (tid == 0)
            __hip_atomic_fetch_add(scat_cnt, 1u, __ATOMIC_ACQ_REL,
                                   __HIP_MEMORY_SCOPE_AGENT);
    } else if (bid == HB) {
        // --- zero accumulators/counters, wait hists, scan, publish ---
        if (tid == 0) {
            *loss_sum = 0.0f; *valid_sum = 0.0f;
            __hip_atomic_store(done, 0u, __ATOMIC_RELAXED, __HIP_MEMORY_SCOPE_AGENT);
            __hip_atomic_store(scat_cnt, 0u, __ATOMIC_RELAXED, __HIP_MEMORY_SCOPE_AGENT);
        }
        if (tid < HB) spin_eq(&hist_flags[tid], MAGIC1);
        __syncthreads();
        __threadfence();
        // Thread t owns bins 4t..4t+3; sum across the 8 slabs.
        int c0 = 0, c1 = 0, c2 = 0, c3 = 0;
        for (int s = 0; s < HB; ++s) {
            const uint16_t* slb = blockHist + s * K + 4 * tid;
            c0 += slb[0]; c1 += slb[1]; c2 += slb[2]; c3 += slb[3];
        }
        const int s4 = c0 + c1 + c2 + c3;
        const int lane = tid & 63, wv = tid >> 6;
        int incl = s4;
        for (int d = 1; d < 64; d <<= 1) {
            const int o = __shfl_up(incl, d, 64);
            if (lane >= d) incl += o;
        }
        if (lane == 63) wsum[wv] = incl;
        __syncthreads();
        int wbase = 0;
        for (int w = 0; w < wv; ++w) wbase += wsum[w];
        incl += wbase;
        const int excl = incl - s4;
        bin_start[4 * tid + 1] = excl + c0;
        bin_start[4 * tid + 2] = excl + c0 + c1;
        bin_start[4 * tid + 3] = excl + c0 + c1 + c2;
        bin_start[4 * tid + 4] = excl + s4;
        if (tid == 0) bin_start[0] = 0;
        cursor[4 * tid + 0] = excl;
        cursor[4 * tid + 1] = excl + c0;
        cursor[4 * tid + 2] = excl + c0 + c1;
        cursor[4 * tid + 3] = excl + c0 + c1 + c2;
        __threadfence();
        __syncthreads();
        if (tid == 0)
            __hip_atomic_store(scan_flag, MAGIC2, __ATOMIC_RELEASE,
                               __HIP_MEMORY_SCOPE_AGENT);
    }

    // ================= all blocks: wait for sort completion =================
    if (tid == 0) spin_eq(scat_cnt, (unsigned int)HB);
    __syncthreads();
    __threadfence();

    // ================= rows phase (identical logic to R8/R9) ================
    const int lane = tid & 63;
    const int wv   = tid >> 6;
    const int row  = (bid << 2) + wv;

    const float ti = targets[row];
    const uint32_t base = (uint32_t)row << 13;   // row * B

    const float cutn = ti - 0.1f;
    int bl = (int)floorf((cutn - 1e-4f) * (float)K);
    int bh = (int)floorf((cutn + 1e-4f) * (float)K) + 1;
    bl = bl < 0 ? 0 : (bl > K ? K : bl);
    bh = bh < 0 ? 0 : (bh > K ? K : bh);
    const int un_end = bin_start[bl];   // unchecked neg: [0, un_end)
    const int cn_end = bin_start[bh];   // checked  neg: [un_end, cn_end)

    const float cutp = ti + 0.1f;
    int pl = (int)floorf((cutp - 1e-4f) * (float)K);
    int ph = (int)floorf((cutp + 1e-4f) * (float)K) + 1;
    pl = pl < 0 ? 0 : (pl > K ? K : pl);
    ph = ph < 0 ? 0 : (ph > K ? K : ph);
    const int cp_beg = bin_start[pl];   // checked  pos: [cp_beg, up_beg)
    const int up_beg = bin_start[ph];   // unchecked pos: [up_beg, B)

    uint32_t Hn = 0, Jn = 0xFFFFFFFFu;
    bool fn = false;
    scan_main<KN.a, KN.b>(sorted_idx, 0, un_end, lane, base + KN.b, Hn, Jn);
    scan_bnd<KN.a, KN.b, true>(sorted_t, sorted_idx, un_end, cn_end, lane, ti,
                               base + KN.b, Hn, Jn, fn);
    const bool valid_n = (un_end > 0) || __any(fn);

    uint32_t Hp = 0, Jp = 0xFFFFFFFFu;
    bool fp2 = false;
    scan_main<KP.a, KP.b>(sorted_idx, up_beg, B, lane, base + KP.b, Hp, Jp);
    scan_bnd<KP.a, KP.b, false>(sorted_t, sorted_idx, cp_beg, up_beg, lane, ti,
                                base + KP.b, Hp, Jp, fp2);
    const bool valid_p = (up_beg < B) || __any(fp2);

    for (int off = 32; off > 0; off >>= 1) {
        const uint32_t ohn = __shfl_down(Hn, off, 64);
        const uint32_t ojn = __shfl_down(Jn, off, 64);
        if (ohn > Hn || (ohn == Hn && ojn < Jn)) { Hn = ohn; Jn = ojn; }
        const uint32_t ohp = __shfl_down(Hp, off, 64);
        const uint32_t ojp = __shfl_down(Jp, off, 64);
        if (ohp > Hp || (ohp == Hp && ojp < Jp)) { Hp = ohp; Jp = ojp; }
    }

    if (lane == 0) {
        float loss = 0.0f, valid = 0.0f;
        if (valid_n && valid_p) {
            const float per = 0.5f - (preds[Jp & 8191u] - preds[Jn & 8191u]);
            loss = per > 0.0f ? per : 0.0f;
            valid = 1.0f;
        }
        sl[wv] = loss; sv[wv] = valid;
    }
    __syncthreads();
    if (tid == 0) {
        atomicAdd(loss_sum,  sl[0] + sl[1] + sl[2] + sl[3]);
        atomicAdd(valid_sum, sv[0] + sv[1] + sv[2] + sv[3]);
        __threadfence();
        const unsigned int old = atomicAdd(done, 1u);
        if (old == gridDim.x - 1u) {          // last block finalizes
            const float ls = atomicAdd(loss_sum, 0.0f);
            const float vs = atomicAdd(valid_sum, 0.0f);
            out[0] = vs > 0.0f ? ls / fmaxf(vs, 1.0f) : 0.0f;
        }
    }
}

extern "C" void kernel_launch(void* const* d_in, const int* in_sizes, int n_in,
                              void* d_out, int out_size, void* d_ws, size_t ws_size,
                              hipStream_t stream) {
    const float* preds   = (const float*)d_in[0];
    const float* targets = (const float*)d_in[1];

    // Workspace (float-word offsets), watermark 57.1 KB (= R9 proven).
    // blockHist overlays sorted_t words 0..4095 (dead before scatter writes).
    // Control words live inside the over-read slack after sorted_idx — safe:
    // over-reads only load-and-discard; max touched entry is 8447 (word 12415).
    float* ws = (float*)d_ws;
    float*        sorted_t   = ws;                        // words 0..8191
    uint16_t*     blockHist  = (uint16_t*)ws;             // words 0..4095 (overlay)
    uint16_t*     sorted_idx = (uint16_t*)(ws + 8192);    // words 8192..12287
    //            over-read slack: words 12288..12543
    unsigned int* hist_flags = (unsigned int*)(ws + 12448);  // 8 words
    unsigned int* scan_flag  = (unsigned int*)(ws + 12456);
    unsigned int* scat_cnt   = (unsigned int*)(ws + 12457);
    float*        loss_sum   = ws + 12458;
    float*        valid_sum  = ws + 12459;
    unsigned int* done       = (unsigned int*)(ws + 12460);
    int*          bin_start  = (int*)(ws + 12544);        // 1025 ints
    int*          cursor     = (int*)(ws + 13600);        // 1024 ints

    fused_kernel<<<B / 4, 256, 0, stream>>>(preds, targets, sorted_t, sorted_idx,
                                            blockHist, bin_start, cursor,
                                            hist_flags, scan_flag, scat_cnt,
                                            loss_sum, valid_sum, done,
                                            (float*)d_out);
}

// Round 11
// 173.701 us; speedup vs baseline: 3.6305x; 3.6305x over previous
//
#include <hip/hip_runtime.h>
#include <stdint.h>

// TripletRankingLoss, bit-exact JAX threefry (partitionable) replication.
// R11: 2 dispatches (R8 structure) + fast LDS-staged single-block sort:
// scatter goes into LDS (48 KB staging) instead of 16K random global stores,
// then dumps coalesced. rows_kernel byte-identical to R8/R9 (128us, ~VALU
// floor). Intra-kernel spin-sync BANNED (R10: cache-storm, 3.4x regression);
// unroll-8 BANNED (R5-R7 poison). Floor model: 128 rows + ~10 sort + ~22
// dispatch/graph overhead = ~160us.

#define B 8192
#define K 1024

struct TFOut { uint32_t a, b; };

__host__ __device__ constexpr uint32_t rotl32(uint32_t x, int r) {
    return (x << r) | (x >> (32 - r));
}

// Full Threefry-2x32 (20 rounds), exactly as jax/_src/prng.py — compile-time
// only, to derive the split keys.
__host__ __device__ constexpr TFOut threefry_full(uint32_t k0, uint32_t k1,
                                                  uint32_t x0, uint32_t x1) {
    const uint32_t ks2 = k0 ^ k1 ^ 0x1BD11BDAu;
    x0 += k0; x1 += k1;
    x0 += x1; x1 = rotl32(x1,13); x1 ^= x0;
    x0 += x1; x1 = rotl32(x1,15); x1 ^= x0;
    x0 += x1; x1 = rotl32(x1,26); x1 ^= x0;
    x0 += x1; x1 = rotl32(x1,6);  x1 ^= x0;
    x0 += k1; x1 += ks2 + 1u;
    x0 += x1; x1 = rotl32(x1,17); x1 ^= x0;
    x0 += x1; x1 = rotl32(x1,29); x1 ^= x0;
    x0 += x1; x1 = rotl32(x1,16); x1 ^= x0;
    x0 += x1; x1 = rotl32(x1,24); x1 ^= x0;
    x0 += ks2; x1 += k0 + 2u;
    x0 += x1; x1 = rotl32(x1,13); x1 ^= x0;
    x0 += x1; x1 = rotl32(x1,15); x1 ^= x0;
    x0 += x1; x1 = rotl32(x1,26); x1 ^= x0;
    x0 += x1; x1 = rotl32(x1,6);  x1 ^= x0;
    x0 += k0; x1 += k1 + 3u;
    x0 += x1; x1 = rotl32(x1,17); x1 ^= x0;
    x0 += x1; x1 = rotl32(x1,29); x1 ^= x0;
    x0 += x1; x1 = rotl32(x1,16); x1 ^= x0;
    x0 += x1; x1 = rotl32(x1,24); x1 ^= x0;
    x0 += k1; x1 += ks2 + 4u;
    x0 += x1; x1 = rotl32(x1,13); x1 ^= x0;
    x0 += x1; x1 = rotl32(x1,15); x1 ^= x0;
    x0 += x1; x1 = rotl32(x1,26); x1 ^= x0;
    x0 += x1; x1 = rotl32(x1,6);  x1 ^= x0;
    x0 += ks2; x1 += k0 + 5u;
    return TFOut{x0, x1};
}

// jax.random.key(42) -> (0,42); partitionable split: kp=block(0,0), kn=block(0,1).
constexpr TFOut KP = threefry_full(0u, 42u, 0u, 0u);
constexpr TFOut KN = threefry_full(0u, 42u, 0u, 1u);

// Device-fast threefry: x0=0 implicit, keys compile-time, caller passes
// x1 pre-keyed (= f + K1). alignbit guarantees 1-inst rotates.
template<uint32_t TK0, uint32_t TK1>
__device__ __forceinline__ uint32_t tf_bits(uint32_t x1) {
    constexpr uint32_t KS2 = TK0 ^ TK1 ^ 0x1BD11BDAu;
    uint32_t x0 = TK0;
#define RND(r) x0 += x1; x1 = __builtin_amdgcn_alignbit(x1, x1, 32 - (r)); x1 ^= x0;
    RND(13) RND(15) RND(26) RND(6)
    x0 += TK1; x1 += KS2 + 1u;
    RND(17) RND(29) RND(16) RND(24)
    x0 += KS2; x1 += TK0 + 2u;
    RND(13) RND(15) RND(26) RND(6)
    x0 += TK0; x1 += TK1 + 3u;
    RND(17) RND(29) RND(16) RND(24)
    x0 += TK1; x1 += KS2 + 4u;
    RND(13) RND(15) RND(26) RND(6)
    x0 += KS2; x1 += TK0 + 5u;
#undef RND
    return x0 ^ x1;
}

__device__ __forceinline__ void mrg(uint32_t& H, uint32_t& J, uint32_t h2, uint32_t j2) {
    if (h2 > H || (h2 == H && j2 < J)) { H = h2; J = j2; }  // j tie: smaller wins
}

// Unchecked-zone scan: every element passes the predicate by construction.
// Unroll-4, preload next group (over-read past `end` stays inside d_ws).
template<uint32_t TK0, uint32_t TK1>
__device__ __forceinline__ void scan_main(const uint16_t* __restrict__ idx,
                                          int beg, int end, int lane,
                                          uint32_t kb, uint32_t& H, uint32_t& J)
{
    uint32_t h0 = 0, h1 = 0, h2 = 0, h3 = 0;
    uint32_t j0 = 0xFFFFFFFFu, j1 = 0xFFFFFFFFu, j2 = 0xFFFFFFFFu, j3 = 0xFFFFFFFFu;
    int s = beg;
    uint32_t a = 0, b = 0, c = 0, d = 0;
    if (s + 256 <= end) {
        a = idx[s + lane];       b = idx[s + lane + 64];
        c = idx[s + lane + 128]; d = idx[s + lane + 192];
    }
    while (s + 256 <= end) {
        const int sn = s + 256;
        const uint32_t na = idx[sn + lane];        // in flight across the 4 hashes
        const uint32_t nb = idx[sn + lane + 64];
        const uint32_t nc = idx[sn + lane + 128];
        const uint32_t nd = idx[sn + lane + 192];
        const uint32_t ha = tf_bits<TK0, TK1>(a + kb) >> 9;
        const uint32_t hb = tf_bits<TK0, TK1>(b + kb) >> 9;
        const uint32_t hc = tf_bits<TK0, TK1>(c + kb) >> 9;
        const uint32_t hd = tf_bits<TK0, TK1>(d + kb) >> 9;
        if (ha > h0) { h0 = ha; j0 = a; }
        if (hb > h1) { h1 = hb; j1 = b; }
        if (hc > h2) { h2 = hc; j2 = c; }
        if (hd > h3) { h3 = hd; j3 = d; }
        a = na; b = nb; c = nc; d = nd;
        s = sn;
    }
    for (int t = s + lane; t < end; t += 64) {
        const uint32_t j = idx[t];
        const uint32_t hh = tf_bits<TK0, TK1>(j + kb) >> 9;
        if (hh > h0) { h0 = hh; j0 = j; }
    }
    mrg(h0, j0, h1, j1); mrg(h2, j2, h3, j3); mrg(h0, j0, h2, j2);
    mrg(H, J, h0, j0);
}

// Boundary zone (~16 elems/row): exact fp32 predicate per element.
template<uint32_t TK0, uint32_t TK1, bool NEG>
__device__ __forceinline__ void scan_bnd(const float* __restrict__ st,
                                         const uint16_t* __restrict__ idx,
                                         int beg, int end, int lane, float ti,
                                         uint32_t kb, uint32_t& H, uint32_t& J,
                                         bool& found)
{
    for (int t = beg + lane; t < end; t += 64) {
        const float tj = st[t];
        const uint32_t j = idx[t];
        const uint32_t hh = tf_bits<TK0, TK1>(j + kb) >> 9;
        const float dd = ti - tj;
        const bool ok = NEG ? (dd > 0.1f) : (dd < -0.1f);
        if (ok) {
            found = true;
            if (hh > H || (hh == H && j < J)) { H = hh; J = j; }
        }
    }
}

// ------------- Kernel A: LDS-staged counting sort + accumulator init --------
// Single block, 1024 threads. Scatter lands in LDS (fast), then dumps to
// global fully coalesced (float4 / uint4).
__global__ __launch_bounds__(1024) void sort_kernel(
    const float* __restrict__ targets,
    float* __restrict__ sorted_t, uint16_t* __restrict__ sorted_idx,
    int* __restrict__ bin_start, float* __restrict__ loss_sum,
    float* __restrict__ valid_sum, unsigned int* __restrict__ done)
{
    __shared__ int hist[K];                       //  4 KB
    __shared__ int cursor[K];                     //  4 KB
    __shared__ int wsum[16];
    __shared__ float st_lds[B];                   // 32 KB
    __shared__ __align__(16) uint16_t si_lds[B];  // 16 KB   (total ~56 KB)
    const int tid = threadIdx.x;

    hist[tid] = 0;
    if (tid == 0) { *loss_sum = 0.0f; *valid_sum = 0.0f; *done = 0u; }
    __syncthreads();

    // Load 8 elements/thread as 2x float4 (coalesced).
    const float4* t4 = reinterpret_cast<const float4*>(targets);
    const float4 va = t4[tid];
    const float4 vb = t4[tid + 1024];
    float v[8] = {va.x, va.y, va.z, va.w, vb.x, vb.y, vb.z, vb.w};
    int   bn[8];
#pragma unroll
    for (int i = 0; i < 8; ++i) {
        int b = (int)(v[i] * (float)K);
        b = b < 0 ? 0 : (b > K - 1 ? K - 1 : b);
        bn[i] = b;
        atomicAdd(&hist[b], 1);
    }
    __syncthreads();

    // shfl-based inclusive scan over 1024 bins (1 bin/thread) — proven R8 code.
    const int cnt  = hist[tid];
    const int lane = tid & 63;
    const int wv   = tid >> 6;
    int incl = cnt;
    for (int d = 1; d < 64; d <<= 1) {
        const int o = __shfl_up(incl, d, 64);
        if (lane >= d) incl += o;
    }
    if (lane == 63) wsum[wv] = incl;
    __syncthreads();
    if (tid < 16) {
        int wincl = wsum[tid];
        for (int d = 1; d < 16; d <<= 1) {
            const int o = __shfl_up(wincl, d, 64);
            if (tid >= d) wincl += o;
        }
        wsum[tid] = wincl;
    }
    __syncthreads();
    incl += (wv > 0) ? wsum[wv - 1] : 0;
    bin_start[tid + 1] = incl;
    if (tid == 0) bin_start[0] = 0;
    cursor[tid] = incl - cnt;
    __syncthreads();

    // Scatter into LDS staging (element e for v[i]: i<4 -> 4*tid+i, else 4096+4*tid+i-4).
#pragma unroll
    for (int i = 0; i < 8; ++i) {
        const int e = (i < 4) ? (4 * tid + i) : (4096 + 4 * tid + (i - 4));
        const int p = atomicAdd(&cursor[bn[i]], 1);
        st_lds[p] = v[i];
        si_lds[p] = (uint16_t)e;
    }
    __syncthreads();

    // Coalesced dump to global.
    reinterpret_cast<float4*>(sorted_t)[tid]        = reinterpret_cast<float4*>(st_lds)[tid];
    reinterpret_cast<float4*>(sorted_t)[tid + 1024] = reinterpret_cast<float4*>(st_lds)[tid + 1024];
    reinterpret_cast<uint4*>(sorted_idx)[tid]       = reinterpret_cast<uint4*>(si_lds)[tid];
}

// ------------- Kernel B: per-wave row scan + fused finalize -----------------
// (byte-identical to R8/R9's passing rows_kernel)
__global__ __launch_bounds__(256) void rows_kernel(
    const float* __restrict__ preds, const float* __restrict__ targets,
    const float* __restrict__ sorted_t, const uint16_t* __restrict__ sorted_idx,
    const int* __restrict__ bin_start,
    float* __restrict__ loss_sum, float* __restrict__ valid_sum,
    unsigned int* __restrict__ done, float* __restrict__ out)
{
    __shared__ float sl[4], sv[4];
    const int lane = threadIdx.x & 63;
    const int wv   = threadIdx.x >> 6;
    const int row  = (blockIdx.x << 2) + wv;

    const float ti = targets[row];
    const uint32_t base = (uint32_t)row << 13;   // row * B

    // Candidate ranges from bins (1e-4 conservative margin >> fp32 ulp slack;
    // boundary zone gets the exact fp32 predicate).
    const float cutn = ti - 0.1f;
    int bl = (int)floorf((cutn - 1e-4f) * (float)K);
    int bh = (int)floorf((cutn + 1e-4f) * (float)K) + 1;
    bl = bl < 0 ? 0 : (bl > K ? K : bl);
    bh = bh < 0 ? 0 : (bh > K ? K : bh);
    const int un_end = bin_start[bl];   // unchecked neg: [0, un_end)
    const int cn_end = bin_start[bh];   // checked  neg: [un_end, cn_end)

    const float cutp = ti + 0.1f;
    int pl = (int)floorf((cutp - 1e-4f) * (float)K);
    int ph = (int)floorf((cutp + 1e-4f) * (float)K) + 1;
    pl = pl < 0 ? 0 : (pl > K ? K : pl);
    ph = ph < 0 ? 0 : (ph > K ? K : ph);
    const int cp_beg = bin_start[pl];   // checked  pos: [cp_beg, up_beg)
    const int up_beg = bin_start[ph];   // unchecked pos: [up_beg, B)

    uint32_t Hn = 0, Jn = 0xFFFFFFFFu;
    bool fn = false;
    scan_main<KN.a, KN.b>(sorted_idx, 0, un_end, lane, base + KN.b, Hn, Jn);
    scan_bnd<KN.a, KN.b, true>(sorted_t, sorted_idx, un_end, cn_end, lane, ti,
                               base + KN.b, Hn, Jn, fn);
    const bool valid_n = (un_end > 0) || __any(fn);

    uint32_t Hp = 0, Jp = 0xFFFFFFFFu;
    bool fp2 = false;
    scan_main<KP.a, KP.b>(sorted_idx, up_beg, B, lane, base + KP.b, Hp, Jp);
    scan_bnd<KP.a, KP.b, false>(sorted_t, sorted_idx, cp_beg, up_beg, lane, ti,
                                base + KP.b, Hp, Jp, fp2);
    const bool valid_p = (up_beg < B) || __any(fp2);

    // In-wave (h, j) max-reduction with first-index tie-break.
    for (int off = 32; off > 0; off >>= 1) {
        const uint32_t ohn = __shfl_down(Hn, off, 64);
        const uint32_t ojn = __shfl_down(Jn, off, 64);
        if (ohn > Hn || (ohn == Hn && ojn < Jn)) { Hn = ohn; Jn = ojn; }
        const uint32_t ohp = __shfl_down(Hp, off, 64);
        const uint32_t ojp = __shfl_down(Jp, off, 64);
        if (ohp > Hp || (ohp == Hp && ojp < Jp)) { Hp = ohp; Jp = ojp; }
    }

    if (lane == 0) {
        float loss = 0.0f, valid = 0.0f;
        if (valid_n && valid_p) {
            const float per = 0.5f - (preds[Jp & 8191u] - preds[Jn & 8191u]);
            loss = per > 0.0f ? per : 0.0f;
            valid = 1.0f;
        }
        sl[wv] = loss; sv[wv] = valid;
    }
    __syncthreads();
    if (threadIdx.x == 0) {
        atomicAdd(loss_sum,  sl[0] + sl[1] + sl[2] + sl[3]);
        atomicAdd(valid_sum, sv[0] + sv[1] + sv[2] + sv[3]);
        __threadfence();
        const unsigned int old = atomicAdd(done, 1u);
        if (old == gridDim.x - 1u) {          // last block finalizes
            const float ls = atomicAdd(loss_sum, 0.0f);
            const float vs = atomicAdd(valid_sum, 0.0f);
            out[0] = vs > 0.0f ? ls / fmaxf(vs, 1.0f) : 0.0f;
        }
    }
}

extern "C" void kernel_launch(void* const* d_in, const int* in_sizes, int n_in,
                              void* d_out, int out_size, void* d_ws, size_t ws_size,
                              hipStream_t stream) {
    const float* preds   = (const float*)d_in[0];
    const float* targets = (const float*)d_in[1];

    // Layout identical to R4/R8 (proven): watermark ~57.4 KB. The 256 words
    // (512 u16 entries) after sorted_idx are the unroll-4 over-read slack.
    float* ws = (float*)d_ws;
    float*        sorted_t   = ws;                       // B floats
    uint16_t*     sorted_idx = (uint16_t*)(ws + B);      // B u16 + slack
    int*          bin_start  = (int*)(ws + B + B / 2 + 256); // K+1 ints
    float*        loss_sum   = ws + B + B / 2 + 2048;
    float*        valid_sum  = loss_sum + 1;
    unsigned int* done       = (unsigned int*)(loss_sum + 2);

    sort_kernel<<<1, 1024, 0, stream>>>(targets, sorted_t, sorted_idx, bin_start,
                                        loss_sum, valid_sum, done);
    rows_kernel<<<B / 4, 256, 0, stream>>>(preds, targets, sorted_t, sorted_idx,
                                           bin_start, loss_sum, valid_sum, done,
                                           (float*)d_out);
}